// Round 1
// baseline (17238.557 us; speedup 1.0000x reference)
//
#include <hip/hip_runtime.h>
#include <math.h>

#define Dm 768
#define Tn 8
#define Nn 197
#define Sn 1576
#define NHn 12
#define DHn 64
#define MLPn 3072
#define NPn 196

// ---------------- im2col: x[1,8,3,224,224] -> P[1568,768] ----------------
__global__ __launch_bounds__(256) void im2col_k(const float* __restrict__ x, float* __restrict__ P) {
    int idx = blockIdx.x * 256 + threadIdx.x;
    if (idx >= 1568 * 768) return;
    int c = idx % 768, r = idx / 768;
    int p = r % 196, t = r / 196;
    int hp = p / 14, wp = p % 14;
    int ch = c / 256, rem = c % 256, py = rem / 16, px = rem % 16;
    P[idx] = x[((t * 3 + ch) * 224 + hp * 16 + py) * 224 + wp * 16 + px];
}

// ---------------- transpose W_patch [768(D),768(K)] -> Wt[K,N] ----------------
__global__ __launch_bounds__(256) void transpose_k(const float* __restrict__ Ws, float* __restrict__ Wd) {
    int idx = blockIdx.x * 256 + threadIdx.x;
    if (idx >= 768 * 768) return;
    int r = idx / 768, c = idx % 768;
    Wd[idx] = Ws[c * 768 + r];
}

// ---------------- scramble + cls + pos -> h[1576,768] ----------------
// scr[t,i,j] = emb[t, (i*768+j)%196, (i*768+j)/196]
__global__ __launch_bounds__(256) void build_h_k(const float* __restrict__ emb, const float* __restrict__ cls,
                                                 const float* __restrict__ pos, float* __restrict__ h) {
    int idx = blockIdx.x * 256 + threadIdx.x;
    if (idx >= Sn * Dm) return;
    int d = idx % Dm, s = idx / Dm;
    int t = s / Nn, r = s % Nn;
    float v;
    if (r == 0) {
        v = cls[d];
    } else {
        int f = (r - 1) * Dm + d;
        int p = f % NPn, dd = f / NPn;
        v = emb[(size_t)(t * NPn + p) * Dm + dd];
    }
    h[idx] = v + pos[r * Dm + d];
}

// ---------------- LayerNorm: one block (256 thr) per row of 768 ----------------
__global__ __launch_bounds__(256) void ln_k(const float* __restrict__ X, const float* __restrict__ g,
                                            const float* __restrict__ bta, float* __restrict__ Y) {
    int row = blockIdx.x;
    const float* x = X + (size_t)row * Dm;
    float s = 0.f, s2 = 0.f;
#pragma unroll
    for (int q = 0; q < 3; ++q) {
        float v = x[threadIdx.x + q * 256];
        s += v; s2 += v * v;
    }
#pragma unroll
    for (int off = 1; off < 64; off <<= 1) {
        s  += __shfl_xor(s,  off);
        s2 += __shfl_xor(s2, off);
    }
    __shared__ float red[8];
    int wv = threadIdx.x >> 6;
    if ((threadIdx.x & 63) == 0) { red[wv * 2] = s; red[wv * 2 + 1] = s2; }
    __syncthreads();
    s  = red[0] + red[2] + red[4] + red[6];
    s2 = red[1] + red[3] + red[5] + red[7];
    float mu  = s * (1.f / 768.f);
    float var = s2 * (1.f / 768.f) - mu * mu;
    float rstd = rsqrtf(var + 1e-5f);
#pragma unroll
    for (int q = 0; q < 3; ++q) {
        int i = threadIdx.x + q * 256;
        float v = x[i];
        Y[(size_t)row * Dm + i] = (v - mu) * rstd * g[i] + bta[i];
    }
}

// ---------------- generic fp32 GEMM: C[M,N] = [Cin +] A[M,K]@B[K,N] [+bias] [gelu] ----------------
template <bool BIAS, bool GELU_ACT, bool RESID>
__global__ __launch_bounds__(256) void gemm_k(const float* __restrict__ A, const float* __restrict__ B,
                                              const float* __restrict__ bias, float* __restrict__ C,
                                              int M, int N, int K) {
    __shared__ float As[16][68];   // [k][m], padded: 68*4B = 272B = 17*16B (b128-aligned, conflict-light)
    __shared__ float Bs[16][64];   // [k][n]
    int tid = threadIdx.x;
    int tx = tid & 15, ty = tid >> 4;
    int m0 = blockIdx.y * 64, n0 = blockIdx.x * 64;
    float acc[4][4] = {};
    int la_k = tid & 15, la_m = tid >> 4;
    int lb_n = tid & 63, lb_k = tid >> 6;
    for (int k0 = 0; k0 < K; k0 += 16) {
#pragma unroll
        for (int q = 0; q < 4; ++q) {
            int m = la_m + q * 16;
            int gm = m0 + m;
            As[la_k][m] = (gm < M) ? A[(size_t)gm * K + k0 + la_k] : 0.f;
        }
#pragma unroll
        for (int q = 0; q < 4; ++q) {
            int k = lb_k + q * 4;
            Bs[k][lb_n] = B[(size_t)(k0 + k) * N + n0 + lb_n];
        }
        __syncthreads();
#pragma unroll
        for (int k = 0; k < 16; ++k) {
            float4 a4 = *(const float4*)&As[k][ty << 2];
            float4 b4 = *(const float4*)&Bs[k][tx << 2];
            float av[4] = {a4.x, a4.y, a4.z, a4.w};
            float bv[4] = {b4.x, b4.y, b4.z, b4.w};
#pragma unroll
            for (int i = 0; i < 4; ++i)
#pragma unroll
                for (int j = 0; j < 4; ++j) acc[i][j] += av[i] * bv[j];
        }
        __syncthreads();
    }
#pragma unroll
    for (int i = 0; i < 4; ++i) {
        int gm = m0 + (ty << 2) + i;
        if (gm < M) {
            size_t base = (size_t)gm * N + n0 + (tx << 2);
            float4 r;
            float* pr = &r.x;
#pragma unroll
            for (int j = 0; j < 4; ++j) {
                float v = acc[i][j];
                if (BIAS) v += bias[n0 + (tx << 2) + j];
                if (GELU_ACT) v = 0.5f * v * (1.f + erff(v * 0.70710678118654752f));
                if (RESID) v += C[base + j];
                pr[j] = v;
            }
            *(float4*)(C + base) = r;
        }
    }
}

// ---------------- per-(head,frame) mean of V over the 197 tokens ----------------
__global__ __launch_bounds__(64) void vmean_k(const float* __restrict__ qkv, float* __restrict__ vm) {
    int g = blockIdx.x;      // g = h*8 + t
    int h = g >> 3, t = g & 7;
    int d = threadIdx.x;
    float s = 0.f;
    for (int n = 0; n < Nn; ++n)
        s += qkv[(size_t)(t * Nn + n) * 2304 + 1536 + h * 64 + d];
    vm[g * 64 + d] = s * (1.f / 197.f);
}

// ---------------- attention: one wave per query row, online softmax ----------------
// even=1: group g -> h=g>>3, t=g&7, rows/keys = frame t's 197 tokens; adds vmean.
// even=0: group g -> head g, rows/keys = all 1576 tokens.
__global__ __launch_bounds__(256) void attn_k(const float* __restrict__ qkv, float* __restrict__ o,
                                              const float* __restrict__ vm, int even) {
    int g = blockIdx.y;
    int h, sbase, Skv;
    if (even) { h = g >> 3; int t = g & 7; sbase = t * Nn; Skv = Nn; }
    else      { h = g;      sbase = 0;     Skv = Sn; }
    int w = threadIdx.x >> 6, lane = threadIdx.x & 63;
    int qi = blockIdx.x * 4 + w;

    __shared__ float qs[4][64];
    float qv = 0.f;
    if (qi < Skv) qv = qkv[(size_t)(sbase + qi) * 2304 + h * 64 + lane];
    qs[w][lane] = qv;
    __syncthreads();
    const float4* q4 = (const float4*)qs[w];

    float m_run = -INFINITY, l_run = 0.f, oacc = 0.f;
    for (int k0 = 0; k0 < Skv; k0 += 64) {
        int cnt = min(64, Skv - k0);
        float sc = -INFINITY;
        if (lane < cnt) {
            const float4* k4 = (const float4*)(qkv + (size_t)(sbase + k0 + lane) * 2304 + 768 + h * 64);
            float acc = 0.f;
#pragma unroll
            for (int dq = 0; dq < 16; ++dq) {
                float4 a = q4[dq], b = k4[dq];
                acc += a.x * b.x + a.y * b.y + a.z * b.z + a.w * b.w;
            }
            sc = acc * 0.125f;
        }
        float mx = sc;
#pragma unroll
        for (int off = 1; off < 64; off <<= 1) mx = fmaxf(mx, __shfl_xor(mx, off));
        float m_new = fmaxf(m_run, mx);
        float p = expf(sc - m_new);          // sc=-inf -> 0
        float psum = p;
#pragma unroll
        for (int off = 1; off < 64; off <<= 1) psum += __shfl_xor(psum, off);
        float alpha = expf(m_run - m_new);   // first tile: exp(-inf)=0
        l_run = l_run * alpha + psum;
        oacc *= alpha;
        m_run = m_new;
        const float* vbase = qkv + (size_t)(sbase + k0) * 2304 + 1536 + h * 64 + lane;
        for (int kk = 0; kk < cnt; ++kk) {
            float pk = __shfl(p, kk);
            oacc += pk * vbase[(size_t)kk * 2304];
        }
    }
    float res = oacc / l_run;
    if (even) res += vm[g * 64 + lane];
    if (qi < Skv) o[(size_t)(sbase + qi) * Dm + h * 64 + lane] = res;
}

extern "C" void kernel_launch(void* const* d_in, const int* in_sizes, int n_in,
                              void* d_out, int out_size, void* d_ws, size_t ws_size,
                              hipStream_t stream) {
    (void)in_sizes; (void)n_in; (void)out_size; (void)ws_size;
    const float* x       = (const float*)d_in[0];
    const float* W_patch = (const float*)d_in[1];
    const float* b_patch = (const float*)d_in[2];
    const float* cls     = (const float*)d_in[3];
    const float* pos     = (const float*)d_in[4];
    const float* ln1_g   = (const float*)d_in[5];
    const float* ln1_b   = (const float*)d_in[6];
    const float* qkv_w   = (const float*)d_in[7];
    const float* qkv_b   = (const float*)d_in[8];
    const float* proj_w  = (const float*)d_in[9];
    const float* proj_b  = (const float*)d_in[10];
    const float* ln2_g   = (const float*)d_in[11];
    const float* ln2_b   = (const float*)d_in[12];
    const float* fc1_w   = (const float*)d_in[13];
    const float* fc1_b   = (const float*)d_in[14];
    const float* fc2_w   = (const float*)d_in[15];
    const float* fc2_b   = (const float*)d_in[16];
    const float* lnf_g   = (const float*)d_in[17];
    const float* lnf_b   = (const float*)d_in[18];

    float* ws = (float*)d_ws;
    float* P    = ws; ws += 1568 * 768;
    float* Wt   = ws; ws += 768 * 768;
    float* emb  = ws; ws += 1568 * 768;
    float* h    = ws; ws += (size_t)Sn * Dm;
    float* a    = ws; ws += (size_t)Sn * Dm;
    float* qkvb = ws; ws += (size_t)Sn * 2304;
    float* ob   = ws; ws += (size_t)Sn * Dm;
    float* mb   = ws; ws += (size_t)Sn * MLPn;
    float* vm   = ws; ws += 96 * 64;

    // ---- patch embed ----
    im2col_k<<<(1568 * 768 + 255) / 256, 256, 0, stream>>>(x, P);
    transpose_k<<<(768 * 768 + 255) / 256, 256, 0, stream>>>(W_patch, Wt);
    gemm_k<true, false, false><<<dim3(768 / 64, (1568 + 63) / 64), 256, 0, stream>>>(P, Wt, b_patch, emb, 1568, 768, 768);
    build_h_k<<<(Sn * Dm + 255) / 256, 256, 0, stream>>>(emb, cls, pos, h);

    for (int i = 0; i < 12; ++i) {
        ln_k<<<Sn, 256, 0, stream>>>(h, ln1_g + i * Dm, ln1_b + i * Dm, a);
        gemm_k<true, false, false><<<dim3(2304 / 64, (Sn + 63) / 64), 256, 0, stream>>>(
            a, qkv_w + (size_t)i * Dm * 2304, qkv_b + i * 2304, qkvb, Sn, 2304, Dm);
        if ((i & 1) == 0) {
            vmean_k<<<96, 64, 0, stream>>>(qkvb, vm);
            attn_k<<<dim3((Nn + 3) / 4, 96), 256, 0, stream>>>(qkvb, ob, vm, 1);
        } else {
            attn_k<<<dim3((Sn + 3) / 4, 12), 256, 0, stream>>>(qkvb, ob, vm, 0);
        }
        gemm_k<true, false, true><<<dim3(768 / 64, (Sn + 63) / 64), 256, 0, stream>>>(
            ob, proj_w + (size_t)i * Dm * Dm, proj_b + i * Dm, h, Sn, Dm, Dm);
        ln_k<<<Sn, 256, 0, stream>>>(h, ln2_g + i * Dm, ln2_b + i * Dm, a);
        gemm_k<true, true, false><<<dim3(3072 / 64, (Sn + 63) / 64), 256, 0, stream>>>(
            a, fc1_w + (size_t)i * Dm * MLPn, fc1_b + i * MLPn, mb, Sn, MLPn, Dm);
        gemm_k<true, false, true><<<dim3(768 / 64, (Sn + 63) / 64), 256, 0, stream>>>(
            mb, fc2_w + (size_t)i * MLPn * Dm, fc2_b + i * Dm, h, Sn, Dm, MLPn);
    }
    ln_k<<<Sn, 256, 0, stream>>>(h, lnf_g, lnf_b, (float*)d_out);
}

// Round 2
// 4551.339 us; speedup vs baseline: 3.7876x; 3.7876x over previous
//
#include <hip/hip_runtime.h>
#include <math.h>

#define Dm 768
#define Tn 8
#define Nn 197
#define Sn 1576
#define MLPn 3072
#define NPn 196
#define MPAD 1664   // 13*128

typedef unsigned short u16;
typedef __bf16 bf16x8 __attribute__((ext_vector_type(8)));
typedef float f32x4 __attribute__((ext_vector_type(4)));
typedef unsigned int u32x4 __attribute__((ext_vector_type(4)));

__device__ inline u16 f2bf(float f) {
    union { float f; unsigned u; } v; v.f = f;
    unsigned r = v.u + 0x7fffu + ((v.u >> 16) & 1u);
    return (u16)(r >> 16);
}

// ---------------- im2col: x[1,8,3,224,224] -> P[1568,768] bf16 ----------------
__global__ __launch_bounds__(256) void im2col_k(const float* __restrict__ x, u16* __restrict__ P) {
    int idx = blockIdx.x * 256 + threadIdx.x;
    if (idx >= 1568 * 768) return;
    int c = idx % 768, r = idx / 768;
    int p = r % 196, t = r / 196;
    int hp = p / 14, wp = p % 14;
    int ch = c / 256, rem = c % 256, py = rem / 16, px = rem % 16;
    P[idx] = f2bf(x[((t * 3 + ch) * 224 + hp * 16 + py) * 224 + wp * 16 + px]);
}

// ---------------- elementwise fp32 -> bf16 (patch weight, already [N,K]) ----------------
__global__ __launch_bounds__(256) void cvt_k(const float* __restrict__ s, u16* __restrict__ d, int n) {
    int i = blockIdx.x * 256 + threadIdx.x;
    if (i < n) d[i] = f2bf(s[i]);
}

// ---------------- per-layer weight transpose+convert: fp32 [K,N] -> bf16 [N,K] ----------------
// qkv 24x72=1728 tiles | proj 576 | fc1 2304 | fc2 2304  -> 6912 blocks
__global__ __launch_bounds__(256) void cvtT_layer_k(const float* __restrict__ qw, const float* __restrict__ pw,
                                                    const float* __restrict__ f1w, const float* __restrict__ f2w,
                                                    u16* __restrict__ Wq, u16* __restrict__ Wp,
                                                    u16* __restrict__ W1, u16* __restrict__ W2) {
    __shared__ float tile[32][33];
    int bid = blockIdx.x;
    const float* src; u16* dst; int K, N, k0, n0;
    if (bid < 1728)      { src = qw;  dst = Wq; K = 768;  N = 2304; int r = bid;        k0 = (r / 72) * 32; n0 = (r % 72) * 32; }
    else if (bid < 2304) { src = pw;  dst = Wp; K = 768;  N = 768;  int r = bid - 1728; k0 = (r / 24) * 32; n0 = (r % 24) * 32; }
    else if (bid < 4608) { src = f1w; dst = W1; K = 768;  N = 3072; int r = bid - 2304; k0 = (r / 96) * 32; n0 = (r % 96) * 32; }
    else                 { src = f2w; dst = W2; K = 3072; N = 768;  int r = bid - 4608; k0 = (r / 24) * 32; n0 = (r % 24) * 32; }
    int tx = threadIdx.x & 31, ty = threadIdx.x >> 5;
#pragma unroll
    for (int i = 0; i < 4; ++i) tile[ty + 8 * i][tx] = src[(size_t)(k0 + ty + 8 * i) * N + n0 + tx];
    __syncthreads();
#pragma unroll
    for (int i = 0; i < 4; ++i) dst[(size_t)(n0 + ty + 8 * i) * K + k0 + tx] = f2bf(tile[tx][ty + 8 * i]);
}

// ---------------- scramble + cls + pos -> h[1576,768] fp32 ----------------
__global__ __launch_bounds__(256) void build_h_k(const float* __restrict__ emb, const float* __restrict__ cls,
                                                 const float* __restrict__ pos, float* __restrict__ h) {
    int idx = blockIdx.x * 256 + threadIdx.x;
    if (idx >= Sn * Dm) return;
    int d = idx % Dm, s = idx / Dm;
    int t = s / Nn, r = s % Nn;
    float v;
    if (r == 0) v = cls[d];
    else {
        int f = (r - 1) * Dm + d;
        int p = f % NPn, dd = f / NPn;
        v = emb[(size_t)(t * NPn + p) * Dm + dd];
    }
    h[idx] = v + pos[r * Dm + d];
}

// ---------------- LayerNorm (templated output: bf16 for GEMM feed, fp32 for final) ----------------
template <typename OutT>
__global__ __launch_bounds__(256) void ln_k(const float* __restrict__ X, const float* __restrict__ g,
                                            const float* __restrict__ bta, OutT* __restrict__ Y) {
    int row = blockIdx.x;
    const float* x = X + (size_t)row * Dm;
    float s = 0.f, s2 = 0.f;
#pragma unroll
    for (int q = 0; q < 3; ++q) {
        float v = x[threadIdx.x + q * 256];
        s += v; s2 += v * v;
    }
#pragma unroll
    for (int off = 1; off < 64; off <<= 1) {
        s  += __shfl_xor(s,  off);
        s2 += __shfl_xor(s2, off);
    }
    __shared__ float red[8];
    int wv = threadIdx.x >> 6;
    if ((threadIdx.x & 63) == 0) { red[wv * 2] = s; red[wv * 2 + 1] = s2; }
    __syncthreads();
    s  = red[0] + red[2] + red[4] + red[6];
    s2 = red[1] + red[3] + red[5] + red[7];
    float mu  = s * (1.f / 768.f);
    float var = s2 * (1.f / 768.f) - mu * mu;
    float rstd = rsqrtf(var + 1e-5f);
#pragma unroll
    for (int q = 0; q < 3; ++q) {
        int i = threadIdx.x + q * 256;
        float v = (x[i] - mu) * rstd * g[i] + bta[i];
        if constexpr (sizeof(OutT) == 2) Y[(size_t)row * Dm + i] = f2bf(v);
        else                             Y[(size_t)row * Dm + i] = v;
    }
}

// ---------------- MFMA bf16 GEMM: C[M,N] = [Cin +] A[M,K]@Bt[N,K]^T [+bias] [gelu] ----------------
// 128x128 tile, 256 thr (4 waves in 2x2), 16x16x32 bf16 MFMA.
// LDS in fragment-swizzled 16B chunks: chunk c = mblk*64 + lane -> frag read = ds_read_b128 at lane*16B.
template <bool BIAS, bool GELU_ACT, bool RESID, typename OutT>
__global__ __launch_bounds__(256) void mgemm_k(const u16* __restrict__ A, const u16* __restrict__ Bt,
                                               const float* __restrict__ bias, OutT* __restrict__ C,
                                               int M, int N, int K) {
    __shared__ u16 As[4096];
    __shared__ u16 Bs[4096];
    int tid = threadIdx.x;
    int lane = tid & 63, w = tid >> 6;
    int wm = w & 1, wn = w >> 1;
    int m0 = blockIdx.y * 128, n0 = blockIdx.x * 128;
    f32x4 acc[4][4] = {};
    int c0 = tid, c1 = tid + 256;
    int ar0 = ((c0 >> 6) << 4) + (c0 & 15), ac0 = ((c0 >> 4) & 3) << 3;
    int ar1 = ((c1 >> 6) << 4) + (c1 & 15), ac1 = ((c1 >> 4) & 3) << 3;
    const u16* Arow0 = A  + (size_t)(m0 + ar0) * K + ac0;
    const u16* Arow1 = A  + (size_t)(m0 + ar1) * K + ac1;
    const u16* Brow0 = Bt + (size_t)(n0 + ar0) * K + ac0;
    const u16* Brow1 = Bt + (size_t)(n0 + ar1) * K + ac1;
    for (int k0 = 0; k0 < K; k0 += 32) {
        u32x4 a0 = *(const u32x4*)(Arow0 + k0);
        u32x4 a1 = *(const u32x4*)(Arow1 + k0);
        u32x4 b0 = *(const u32x4*)(Brow0 + k0);
        u32x4 b1 = *(const u32x4*)(Brow1 + k0);
        *(u32x4*)(As + c0 * 8) = a0;
        *(u32x4*)(As + c1 * 8) = a1;
        *(u32x4*)(Bs + c0 * 8) = b0;
        *(u32x4*)(Bs + c1 * 8) = b1;
        __syncthreads();
        bf16x8 af[4], bfr[4];
#pragma unroll
        for (int i = 0; i < 4; ++i) {
            af[i]  = *(const bf16x8*)(As + (((wm * 4 + i) * 64 + lane) << 3));
            bfr[i] = *(const bf16x8*)(Bs + (((wn * 4 + i) * 64 + lane) << 3));
        }
#pragma unroll
        for (int mi = 0; mi < 4; ++mi)
#pragma unroll
            for (int ni = 0; ni < 4; ++ni)
                acc[mi][ni] = __builtin_amdgcn_mfma_f32_16x16x32_bf16(af[mi], bfr[ni], acc[mi][ni], 0, 0, 0);
        __syncthreads();
    }
    // C/D layout (16x16): col = lane&15, row = (lane>>4)*4 + reg   [m89/m91 verified]
    int rbase = (lane >> 4) << 2, cl = lane & 15;
#pragma unroll
    for (int mi = 0; mi < 4; ++mi) {
#pragma unroll
        for (int r = 0; r < 4; ++r) {
            int gm = m0 + wm * 64 + mi * 16 + rbase + r;
            if (gm < M) {
#pragma unroll
                for (int ni = 0; ni < 4; ++ni) {
                    int gn = n0 + wn * 64 + ni * 16 + cl;
                    float v = acc[mi][ni][r];
                    if (BIAS) v += bias[gn];
                    if (GELU_ACT) v = 0.5f * v * (1.f + erff(v * 0.7071067811865476f));
                    size_t off = (size_t)gm * N + gn;
                    if (RESID) v += ((const float*)C)[off];
                    if constexpr (sizeof(OutT) == 2) ((u16*)C)[off] = f2bf(v);
                    else                             ((float*)C)[off] = v;
                }
            }
        }
    }
}

// ---------------- per-(head,frame) mean of V ----------------
__global__ __launch_bounds__(64) void vmean_k(const float* __restrict__ qkv, float* __restrict__ vm) {
    int g = blockIdx.x;      // g = h*8 + t
    int h = g >> 3, t = g & 7;
    int d = threadIdx.x;
    float s = 0.f;
    for (int n = 0; n < Nn; ++n)
        s += qkv[(size_t)(t * Nn + n) * 2304 + 1536 + h * 64 + d];
    vm[g * 64 + d] = s * (1.f / 197.f);
}

// ---------------- tiled flash attention: 32 queries/block, 64-key LDS tiles ----------------
// thread: q = tid>>3 (query), sub = tid&7; keys sub+8j; d-slice sub*8..+8 for PV.
__global__ __launch_bounds__(256) void attn_k(const float* __restrict__ qkv, u16* __restrict__ o,
                                              const float* __restrict__ vm, int even) {
    __shared__ float Ks[64][68];
    __shared__ float Vs[64][68];
    __shared__ float Ps[32][66];
    int g = blockIdx.y;
    int h, sbase, Skv;
    if (even) { h = g >> 3; int t = g & 7; sbase = t * Nn; Skv = Nn; }
    else      { h = g; sbase = 0; Skv = Sn; }
    int tid = threadIdx.x;
    int q = tid >> 3, sub = tid & 7;
    int qg = blockIdx.x * 32 + q;
    int qrow = (qg < Skv) ? qg : 0;
    const float* qp = qkv + (size_t)(sbase + qrow) * 2304 + h * 64;
    float4 qreg[16];
#pragma unroll
    for (int i = 0; i < 16; ++i) qreg[i] = *(const float4*)(qp + 4 * i);
    float oacc[8] = {};
    float m_run = -INFINITY, l_run = 0.f;
    for (int kt = 0; kt < Skv; kt += 64) {
        int cnt = min(64, Skv - kt);
        // stage K/V tiles (zero rows >= cnt)
#pragma unroll
        for (int i = 0; i < 4; ++i) {
            int idx = tid + 256 * i;
            int row = idx >> 4, c4 = (idx & 15) << 2;
            float4 kv = make_float4(0.f, 0.f, 0.f, 0.f), vv = kv;
            if (row < cnt) {
                const float* bp = qkv + (size_t)(sbase + kt + row) * 2304 + h * 64 + c4;
                kv = *(const float4*)(bp + 768);
                vv = *(const float4*)(bp + 1536);
            }
            *(float4*)&Ks[row][c4] = kv;
            *(float4*)&Vs[row][c4] = vv;
        }
        __syncthreads();
        // scores for keys sub+8j (8 unique rows/wave -> banks tile fully; same-addr lanes broadcast)
        float s[8] = {};
#pragma unroll
        for (int d4 = 0; d4 < 16; ++d4) {
            float4 qv = qreg[d4];
#pragma unroll
            for (int j = 0; j < 8; ++j) {
                float4 kv = *(const float4*)&Ks[sub + 8 * j][d4 << 2];
                s[j] += qv.x * kv.x + qv.y * kv.y + qv.z * kv.z + qv.w * kv.w;
            }
        }
        float mx = -INFINITY;
#pragma unroll
        for (int j = 0; j < 8; ++j) {
            s[j] = (sub + 8 * j < cnt) ? s[j] * 0.125f : -INFINITY;
            mx = fmaxf(mx, s[j]);
        }
        mx = fmaxf(mx, __shfl_xor(mx, 1, 8));
        mx = fmaxf(mx, __shfl_xor(mx, 2, 8));
        mx = fmaxf(mx, __shfl_xor(mx, 4, 8));
        float m_new = fmaxf(m_run, mx);
        float p[8], psum = 0.f;
#pragma unroll
        for (int j = 0; j < 8; ++j) { p[j] = __expf(s[j] - m_new); psum += p[j]; }
        psum += __shfl_xor(psum, 1, 8);
        psum += __shfl_xor(psum, 2, 8);
        psum += __shfl_xor(psum, 4, 8);
        float alpha = __expf(m_run - m_new);
        l_run = l_run * alpha + psum;
#pragma unroll
        for (int j = 0; j < 8; ++j) oacc[j] *= alpha;
        m_run = m_new;
#pragma unroll
        for (int j = 0; j < 8; ++j) Ps[q][sub + 8 * j] = p[j];
        __syncthreads();
        // PV: this thread owns dims sub*8..+8 of its query
        const float* Pq = Ps[q];
#pragma unroll 4
        for (int k = 0; k < 64; ++k) {
            float pv = Pq[k];
            const float* vp = &Vs[k][sub << 3];
            float4 v1 = *(const float4*)vp, v2 = *(const float4*)(vp + 4);
            oacc[0] += pv * v1.x; oacc[1] += pv * v1.y; oacc[2] += pv * v1.z; oacc[3] += pv * v1.w;
            oacc[4] += pv * v2.x; oacc[5] += pv * v2.y; oacc[6] += pv * v2.z; oacc[7] += pv * v2.w;
        }
        __syncthreads();
    }
    if (qg < Skv) {
        float inv = 1.f / l_run;
#pragma unroll
        for (int j = 0; j < 8; ++j) {
            float v = oacc[j] * inv;
            if (even) v += vm[g * 64 + (sub << 3) + j];
            o[(size_t)(sbase + qg) * Dm + h * 64 + (sub << 3) + j] = f2bf(v);
        }
    }
}

extern "C" void kernel_launch(void* const* d_in, const int* in_sizes, int n_in,
                              void* d_out, int out_size, void* d_ws, size_t ws_size,
                              hipStream_t stream) {
    (void)in_sizes; (void)n_in; (void)out_size; (void)ws_size;
    const float* x       = (const float*)d_in[0];
    const float* W_patch = (const float*)d_in[1];
    const float* b_patch = (const float*)d_in[2];
    const float* cls     = (const float*)d_in[3];
    const float* pos     = (const float*)d_in[4];
    const float* ln1_g   = (const float*)d_in[5];
    const float* ln1_b   = (const float*)d_in[6];
    const float* qkv_w   = (const float*)d_in[7];
    const float* qkv_b   = (const float*)d_in[8];
    const float* proj_w  = (const float*)d_in[9];
    const float* proj_b  = (const float*)d_in[10];
    const float* ln2_g   = (const float*)d_in[11];
    const float* ln2_b   = (const float*)d_in[12];
    const float* fc1_w   = (const float*)d_in[13];
    const float* fc1_b   = (const float*)d_in[14];
    const float* fc2_w   = (const float*)d_in[15];
    const float* fc2_b   = (const float*)d_in[16];
    const float* lnf_g   = (const float*)d_in[17];
    const float* lnf_b   = (const float*)d_in[18];

    char* base = (char*)d_ws;
    auto alloc = [&](size_t bytes) { void* p = base; base += (bytes + 255) & ~(size_t)255; return p; };
    u16*   P    = (u16*)  alloc((size_t)MPAD * 768 * 2);
    u16*   Wq   = (u16*)  alloc((size_t)2304 * 768 * 2);
    u16*   Wp   = (u16*)  alloc((size_t)768 * 768 * 2);
    u16*   W1   = (u16*)  alloc((size_t)3072 * 768 * 2);
    u16*   W2   = (u16*)  alloc((size_t)768 * 3072 * 2);
    float* emb  = (float*)alloc((size_t)1568 * 768 * 4);
    float* h    = (float*)alloc((size_t)Sn * Dm * 4);
    u16*   a    = (u16*)  alloc((size_t)MPAD * 768 * 2);
    float* qkvb = (float*)alloc((size_t)Sn * 2304 * 4);
    u16*   ob   = (u16*)  alloc((size_t)MPAD * 768 * 2);
    u16*   mb   = (u16*)  alloc((size_t)MPAD * 3072 * 2);
    float* vm   = (float*)alloc((size_t)96 * 64 * 4);

    // ---- patch embed ----
    im2col_k<<<(1568 * 768 + 255) / 256, 256, 0, stream>>>(x, P);
    cvt_k<<<(768 * 768 + 255) / 256, 256, 0, stream>>>(W_patch, Wp, 768 * 768);
    mgemm_k<true, false, false, float><<<dim3(6, 13), 256, 0, stream>>>(P, Wp, b_patch, emb, 1568, 768, 768);
    build_h_k<<<(Sn * Dm + 255) / 256, 256, 0, stream>>>(emb, cls, pos, h);

    for (int i = 0; i < 12; ++i) {
        cvtT_layer_k<<<6912, 256, 0, stream>>>(
            qkv_w + (size_t)i * 768 * 2304, proj_w + (size_t)i * 768 * 768,
            fc1_w + (size_t)i * 768 * 3072, fc2_w + (size_t)i * 3072 * 768,
            Wq, Wp, W1, W2);
        ln_k<u16><<<Sn, 256, 0, stream>>>(h, ln1_g + i * Dm, ln1_b + i * Dm, a);
        mgemm_k<true, false, false, float><<<dim3(18, 13), 256, 0, stream>>>(
            a, Wq, qkv_b + i * 2304, qkvb, Sn, 2304, 768);
        if ((i & 1) == 0) {
            vmean_k<<<96, 64, 0, stream>>>(qkvb, vm);
            attn_k<<<dim3(7, 96), 256, 0, stream>>>(qkvb, ob, vm, 1);
        } else {
            attn_k<<<dim3(50, 12), 256, 0, stream>>>(qkvb, ob, vm, 0);
        }
        mgemm_k<true, false, true, float><<<dim3(6, 13), 256, 0, stream>>>(
            ob, Wp, proj_b + i * Dm, h, Sn, 768, 768);
        ln_k<u16><<<Sn, 256, 0, stream>>>(h, ln2_g + i * Dm, ln2_b + i * Dm, a);
        mgemm_k<true, true, false, u16><<<dim3(24, 13), 256, 0, stream>>>(
            a, W1, fc1_b + i * MLPn, mb, Sn, 3072, 768);
        mgemm_k<true, false, true, float><<<dim3(6, 13), 256, 0, stream>>>(
            mb, W2, fc2_b + i * Dm, h, Sn, 768, 3072);
    }
    ln_k<float><<<Sn, 256, 0, stream>>>(h, lnf_g, lnf_b, (float*)d_out);
}

// Round 3
// 2438.792 us; speedup vs baseline: 7.0685x; 1.8662x over previous
//
#include <hip/hip_runtime.h>
#include <math.h>

#define Dm 768
#define Tn 8
#define Nn 197
#define Sn 1576
#define MLPn 3072
#define NPn 196
#define MPAD 1664   // 13*128

typedef unsigned short u16;
typedef __bf16 bf16x8 __attribute__((ext_vector_type(8)));
typedef float f32x4 __attribute__((ext_vector_type(4)));
typedef unsigned int u32x4 __attribute__((ext_vector_type(4)));
typedef u16 u16x8 __attribute__((ext_vector_type(8)));
typedef u16 u16x4 __attribute__((ext_vector_type(4)));

__device__ inline u16 f2bf(float f) {
    union { float f; unsigned u; } v; v.f = f;
    unsigned r = v.u + 0x7fffu + ((v.u >> 16) & 1u);
    return (u16)(r >> 16);
}
__device__ inline float bf2f(u16 v) {
    union { unsigned u; float f; } x; x.u = ((unsigned)v) << 16; return x.f;
}

// ---------------- im2col: x[1,8,3,224,224] -> P[1568,768] bf16 ----------------
__global__ __launch_bounds__(256) void im2col_k(const float* __restrict__ x, u16* __restrict__ P) {
    int idx = blockIdx.x * 256 + threadIdx.x;
    if (idx >= 1568 * 768) return;
    int c = idx % 768, r = idx / 768;
    int p = r % 196, t = r / 196;
    int hp = p / 14, wp = p % 14;
    int ch = c / 256, rem = c % 256, py = rem / 16, px = rem % 16;
    P[idx] = f2bf(x[((t * 3 + ch) * 224 + hp * 16 + py) * 224 + wp * 16 + px]);
}

__global__ __launch_bounds__(256) void cvt_k(const float* __restrict__ s, u16* __restrict__ d, int n) {
    int i = blockIdx.x * 256 + threadIdx.x;
    if (i < n) d[i] = f2bf(s[i]);
}

// ---------------- per-layer weight transpose+convert: fp32 [K,N] -> bf16 [N,K] ----------------
__global__ __launch_bounds__(256) void cvtT_layer_k(const float* __restrict__ qw, const float* __restrict__ pw,
                                                    const float* __restrict__ f1w, const float* __restrict__ f2w,
                                                    u16* __restrict__ Wq, u16* __restrict__ Wp,
                                                    u16* __restrict__ W1, u16* __restrict__ W2) {
    __shared__ float tile[32][33];
    int bid = blockIdx.x;
    const float* src; u16* dst; int K, N, k0, n0;
    if (bid < 1728)      { src = qw;  dst = Wq; K = 768;  N = 2304; int r = bid;        k0 = (r / 72) * 32; n0 = (r % 72) * 32; }
    else if (bid < 2304) { src = pw;  dst = Wp; K = 768;  N = 768;  int r = bid - 1728; k0 = (r / 24) * 32; n0 = (r % 24) * 32; }
    else if (bid < 4608) { src = f1w; dst = W1; K = 768;  N = 3072; int r = bid - 2304; k0 = (r / 96) * 32; n0 = (r % 96) * 32; }
    else                 { src = f2w; dst = W2; K = 3072; N = 768;  int r = bid - 4608; k0 = (r / 24) * 32; n0 = (r % 24) * 32; }
    int tx = threadIdx.x & 31, ty = threadIdx.x >> 5;
#pragma unroll
    for (int i = 0; i < 4; ++i) tile[ty + 8 * i][tx] = src[(size_t)(k0 + ty + 8 * i) * N + n0 + tx];
    __syncthreads();
#pragma unroll
    for (int i = 0; i < 4; ++i) dst[(size_t)(n0 + ty + 8 * i) * K + k0 + tx] = f2bf(tile[tx][ty + 8 * i]);
}

// ---------------- scramble + cls + pos -> h[1576,768] fp32 ----------------
__global__ __launch_bounds__(256) void build_h_k(const float* __restrict__ emb, const float* __restrict__ cls,
                                                 const float* __restrict__ pos, float* __restrict__ h) {
    int idx = blockIdx.x * 256 + threadIdx.x;
    if (idx >= Sn * Dm) return;
    int d = idx % Dm, s = idx / Dm;
    int t = s / Nn, r = s % Nn;
    float v;
    if (r == 0) v = cls[d];
    else {
        int f = (r - 1) * Dm + d;
        int p = f % NPn, dd = f / NPn;
        v = emb[(size_t)(t * NPn + p) * Dm + dd];
    }
    h[idx] = v + pos[r * Dm + d];
}

// ---------------- LayerNorm ----------------
template <typename OutT>
__global__ __launch_bounds__(256) void ln_k(const float* __restrict__ X, const float* __restrict__ g,
                                            const float* __restrict__ bta, OutT* __restrict__ Y) {
    int row = blockIdx.x;
    const float* x = X + (size_t)row * Dm;
    float s = 0.f, s2 = 0.f;
#pragma unroll
    for (int q = 0; q < 3; ++q) {
        float v = x[threadIdx.x + q * 256];
        s += v; s2 += v * v;
    }
#pragma unroll
    for (int off = 1; off < 64; off <<= 1) {
        s  += __shfl_xor(s,  off);
        s2 += __shfl_xor(s2, off);
    }
    __shared__ float red[8];
    int wv = threadIdx.x >> 6;
    if ((threadIdx.x & 63) == 0) { red[wv * 2] = s; red[wv * 2 + 1] = s2; }
    __syncthreads();
    s  = red[0] + red[2] + red[4] + red[6];
    s2 = red[1] + red[3] + red[5] + red[7];
    float mu  = s * (1.f / 768.f);
    float var = s2 * (1.f / 768.f) - mu * mu;
    float rstd = rsqrtf(var + 1e-5f);
#pragma unroll
    for (int q = 0; q < 3; ++q) {
        int i = threadIdx.x + q * 256;
        float v = (x[i] - mu) * rstd * g[i] + bta[i];
        if constexpr (sizeof(OutT) == 2) Y[(size_t)row * Dm + i] = f2bf(v);
        else                             Y[(size_t)row * Dm + i] = v;
    }
}

// ---------------- MFMA bf16 GEMM, split-K: Cp[split][MPAD][N] = A@Bt^T over K-chunk ----------------
__global__ __launch_bounds__(256) void mgemm_k(const u16* __restrict__ A, const u16* __restrict__ Bt,
                                               float* __restrict__ Cp, int N, int Kfull, int Kc) {
    __shared__ u16 As[4096];
    __shared__ u16 Bs[4096];
    int split = blockIdx.z;
    A  += split * Kc;
    Bt += split * Kc;
    Cp += (size_t)split * MPAD * N;
    int tid = threadIdx.x;
    int lane = tid & 63, w = tid >> 6;
    int wm = w & 1, wn = w >> 1;
    int m0 = blockIdx.y * 128, n0 = blockIdx.x * 128;
    f32x4 acc[4][4] = {};
    int c0 = tid, c1 = tid + 256;
    int ar0 = ((c0 >> 6) << 4) + (c0 & 15), ac0 = ((c0 >> 4) & 3) << 3;
    int ar1 = ((c1 >> 6) << 4) + (c1 & 15), ac1 = ((c1 >> 4) & 3) << 3;
    const u16* Arow0 = A  + (size_t)(m0 + ar0) * Kfull + ac0;
    const u16* Arow1 = A  + (size_t)(m0 + ar1) * Kfull + ac1;
    const u16* Brow0 = Bt + (size_t)(n0 + ar0) * Kfull + ac0;
    const u16* Brow1 = Bt + (size_t)(n0 + ar1) * Kfull + ac1;
    for (int k0 = 0; k0 < Kc; k0 += 32) {
        u32x4 a0 = *(const u32x4*)(Arow0 + k0);
        u32x4 a1 = *(const u32x4*)(Arow1 + k0);
        u32x4 b0 = *(const u32x4*)(Brow0 + k0);
        u32x4 b1 = *(const u32x4*)(Brow1 + k0);
        *(u32x4*)(As + c0 * 8) = a0;
        *(u32x4*)(As + c1 * 8) = a1;
        *(u32x4*)(Bs + c0 * 8) = b0;
        *(u32x4*)(Bs + c1 * 8) = b1;
        __syncthreads();
        bf16x8 af[4], bfr[4];
#pragma unroll
        for (int i = 0; i < 4; ++i) {
            af[i]  = *(const bf16x8*)(As + (((wm * 4 + i) * 64 + lane) << 3));
            bfr[i] = *(const bf16x8*)(Bs + (((wn * 4 + i) * 64 + lane) << 3));
        }
#pragma unroll
        for (int mi = 0; mi < 4; ++mi)
#pragma unroll
            for (int ni = 0; ni < 4; ++ni)
                acc[mi][ni] = __builtin_amdgcn_mfma_f32_16x16x32_bf16(af[mi], bfr[ni], acc[mi][ni], 0, 0, 0);
        __syncthreads();
    }
    int rbase = (lane >> 4) << 2, cl = lane & 15;
#pragma unroll
    for (int mi = 0; mi < 4; ++mi)
#pragma unroll
        for (int r = 0; r < 4; ++r) {
            int gm = m0 + wm * 64 + mi * 16 + rbase + r;
#pragma unroll
            for (int ni = 0; ni < 4; ++ni) {
                int gn = n0 + wn * 64 + ni * 16 + cl;
                Cp[(size_t)gm * N + gn] = acc[mi][ni][r];
            }
        }
}

// ---------------- epilogue: sum splits + bias [+gelu] [+resid] -> OutT ----------------
template <bool GELU_ACT, bool RESID, typename OutT>
__global__ __launch_bounds__(256) void ep_k(const float* __restrict__ Cp, const float* __restrict__ bias,
                                            const float* __restrict__ resid, OutT* __restrict__ out,
                                            int N, int S) {
    int row = blockIdx.y;
    int n = blockIdx.x * 1024 + threadIdx.x * 4;
    if (n >= N) return;
    size_t off = (size_t)row * N + n;
    f32x4 acc = *(const f32x4*)(Cp + off);
    for (int s = 1; s < S; ++s)
        acc += *(const f32x4*)(Cp + (size_t)s * MPAD * N + off);
    acc += *(const f32x4*)(bias + n);
    if (GELU_ACT) {
#pragma unroll
        for (int j = 0; j < 4; ++j) acc[j] = 0.5f * acc[j] * (1.f + erff(acc[j] * 0.7071067811865476f));
    }
    if (RESID) acc += *(const f32x4*)(resid + off);
    if constexpr (sizeof(OutT) == 2) {
        u16x4 o;
#pragma unroll
        for (int j = 0; j < 4; ++j) o[j] = f2bf(acc[j]);
        *(u16x4*)((u16*)out + off) = o;
    } else {
        *(f32x4*)((float*)out + off) = acc;
    }
}

// ---------------- per-(head,frame) mean of V (bf16 input) ----------------
__global__ __launch_bounds__(64) void vmean_k(const u16* __restrict__ qkv, float* __restrict__ vm) {
    int g = blockIdx.x;      // g = h*8 + t
    int h = g >> 3, t = g & 7;
    int d = threadIdx.x;
    float s = 0.f;
    for (int n = 0; n < Nn; ++n)
        s += bf2f(qkv[(size_t)(t * Nn + n) * 2304 + 1536 + h * 64 + d]);
    vm[g * 64 + d] = s * (1.f / 197.f);
}

// ---------------- MFMA flash attention ----------------
// block: 4 waves x 32 queries = 128 queries, one (group, key-split). 64-key tiles.
// LDS: Ks[key][dim] bf16 swizzled; Vt[dim][key] bf16 swizzled; Ps per-wave P roundtrip.
// 16B-chunk swizzle: chunk c of row r stored at c ^ (r&7).
__global__ __launch_bounds__(256) void attn_mfma_k(const u16* __restrict__ qkv, float* __restrict__ Ou,
                                                   float* __restrict__ ml, int even, int nsplit,
                                                   int NG, int Sq) {
    __shared__ __align__(16) u16 Ks[64 * 64];
    __shared__ __align__(16) u16 Vt[64 * 64];
    __shared__ __align__(16) u16 Ps[4 * 32 * 64];
    int g = blockIdx.y;
    int h, sbase;
    if (even) { h = g >> 3; sbase = (g & 7) * Nn; } else { h = g; sbase = 0; }
    int split = blockIdx.z;
    int chunk = (Sq + nsplit - 1) / nsplit;
    int kbeg = split * chunk, kend = min(Sq, kbeg + chunk);
    int tid = threadIdx.x, lane = tid & 63, w = tid >> 6;
    int quad = lane >> 4, l15 = lane & 15;
    int q0w = blockIdx.x * 128 + w * 32;
    u16* Pw = Ps + w * 2048;

    // Q A-frags: A[m=l15 (query)][k=quad*8+j + ks*32 (dim)]
    bf16x8 aq[2][2];
#pragma unroll
    for (int mb = 0; mb < 2; ++mb) {
        int qidx = q0w + mb * 16 + l15; if (qidx >= Sq) qidx = Sq - 1;
        const u16* qp = qkv + (size_t)(sbase + qidx) * 2304 + h * 64;
#pragma unroll
        for (int ks = 0; ks < 2; ++ks)
            aq[mb][ks] = *(const bf16x8*)(qp + ks * 32 + quad * 8);
    }
    f32x4 acc_o[2][4] = {};
    float m_run[2][4], l_run[2][4];
#pragma unroll
    for (int mb = 0; mb < 2; ++mb)
#pragma unroll
        for (int r = 0; r < 4; ++r) { m_run[mb][r] = -INFINITY; l_run[mb][r] = 0.f; }

    for (int kt = kbeg; kt < kend; kt += 64) {
        int cnt = kend - kt; if (cnt > 64) cnt = 64;
        // ---- stage K (natural rows, swizzled chunks) ----
        {
            int dc = tid & 7;
#pragma unroll
            for (int p = 0; p < 2; ++p) {
                int row = (tid >> 3) + 32 * p;
                u32x4 kd = {};
                if (row < cnt) kd = *(const u32x4*)(qkv + (size_t)(sbase + kt + row) * 2304 + 768 + h * 64 + dc * 8);
                *(u32x4*)(Ks + row * 64 + ((dc ^ (row & 7)) << 3)) = kd;
            }
        }
        // ---- stage Vt (transposed, swizzled) ----
        {
            int d = (tid & 31) * 2, kc = tid >> 5;
            u16x8 lo, hi;
#pragma unroll
            for (int i = 0; i < 8; ++i) {
                int key = kc * 8 + i;
                unsigned t = 0;
                if (key < cnt) t = *(const unsigned*)(qkv + (size_t)(sbase + kt + key) * 2304 + 1536 + h * 64 + d);
                lo[i] = (u16)(t & 0xffffu); hi[i] = (u16)(t >> 16);
            }
            *(u16x8*)(Vt + d * 64 + ((kc ^ (d & 7)) << 3)) = lo;
            *(u16x8*)(Vt + (d + 1) * 64 + ((kc ^ ((d + 1) & 7)) << 3)) = hi;
        }
        __syncthreads();
        // ---- QK^T: S[2mb][4ni], C-layout row=query(quad*4+reg), col=key(l15+16ni) ----
        f32x4 acc_s[2][4] = {};
#pragma unroll
        for (int ni = 0; ni < 4; ++ni) {
            int key = l15 + ni * 16;
#pragma unroll
            for (int ks = 0; ks < 2; ++ks) {
                bf16x8 bk = *(const bf16x8*)(Ks + key * 64 + ((((ks << 2) + quad) ^ (key & 7)) << 3));
                acc_s[0][ni] = __builtin_amdgcn_mfma_f32_16x16x32_bf16(aq[0][ks], bk, acc_s[0][ni], 0, 0, 0);
                acc_s[1][ni] = __builtin_amdgcn_mfma_f32_16x16x32_bf16(aq[1][ks], bk, acc_s[1][ni], 0, 0, 0);
            }
        }
        // ---- online softmax per mb, write P (bf16) to per-wave LDS ----
#pragma unroll
        for (int mb = 0; mb < 2; ++mb) {
#pragma unroll
            for (int ni = 0; ni < 4; ++ni) {
                int keyabs = kt + l15 + ni * 16;
#pragma unroll
                for (int r = 0; r < 4; ++r) {
                    float sv = acc_s[mb][ni][r] * 0.125f;
                    if (keyabs >= kend) sv = -1e30f;
                    acc_s[mb][ni][r] = sv;
                }
            }
#pragma unroll
            for (int r = 0; r < 4; ++r) {
                float mx = fmaxf(fmaxf(acc_s[mb][0][r], acc_s[mb][1][r]), fmaxf(acc_s[mb][2][r], acc_s[mb][3][r]));
                mx = fmaxf(mx, __shfl_xor(mx, 1));
                mx = fmaxf(mx, __shfl_xor(mx, 2));
                mx = fmaxf(mx, __shfl_xor(mx, 4));
                mx = fmaxf(mx, __shfl_xor(mx, 8));
                float mnew = fmaxf(m_run[mb][r], mx);
                float pv[4], ps = 0.f;
#pragma unroll
                for (int ni = 0; ni < 4; ++ni) { pv[ni] = __expf(acc_s[mb][ni][r] - mnew); ps += pv[ni]; }
                ps += __shfl_xor(ps, 1);
                ps += __shfl_xor(ps, 2);
                ps += __shfl_xor(ps, 4);
                ps += __shfl_xor(ps, 8);
                float alpha = __expf(m_run[mb][r] - mnew);
                l_run[mb][r] = l_run[mb][r] * alpha + ps;
                m_run[mb][r] = mnew;
#pragma unroll
                for (int ni = 0; ni < 4; ++ni) acc_o[mb][ni][r] *= alpha;
                int prow = mb * 16 + quad * 4 + r;
#pragma unroll
                for (int ni = 0; ni < 4; ++ni) {
                    int key = l15 + ni * 16;
                    Pw[prow * 64 + (((key >> 3) ^ (prow & 7)) << 3) + (key & 7)] = f2bf(pv[ni]);
                }
            }
        }
        // ---- PV: A=P[m=query][k=key], B=Vt[k=key][n=dim] ----
        bf16x8 ap[2][2];
#pragma unroll
        for (int mb = 0; mb < 2; ++mb)
#pragma unroll
            for (int ks = 0; ks < 2; ++ks)
                ap[mb][ks] = *(const bf16x8*)(Pw + (mb * 16 + l15) * 64 + ((((ks << 2) + quad) ^ (l15 & 7)) << 3));
#pragma unroll
        for (int ni = 0; ni < 4; ++ni) {
            int d = l15 + ni * 16;
#pragma unroll
            for (int ks = 0; ks < 2; ++ks) {
                bf16x8 bv = *(const bf16x8*)(Vt + d * 64 + ((((ks << 2) + quad) ^ (d & 7)) << 3));
                acc_o[0][ni] = __builtin_amdgcn_mfma_f32_16x16x32_bf16(ap[0][ks], bv, acc_o[0][ni], 0, 0, 0);
                acc_o[1][ni] = __builtin_amdgcn_mfma_f32_16x16x32_bf16(ap[1][ks], bv, acc_o[1][ni], 0, 0, 0);
            }
        }
        __syncthreads();
    }
    // ---- write unnormalized O + (m,l) ----
    size_t gb = ((size_t)split * NG + g) * Sq;
#pragma unroll
    for (int mb = 0; mb < 2; ++mb)
#pragma unroll
        for (int r = 0; r < 4; ++r) {
            int q = q0w + mb * 16 + quad * 4 + r;
            if (q < Sq) {
                float* op = Ou + (gb + q) * 64;
#pragma unroll
                for (int ni = 0; ni < 4; ++ni) op[l15 + ni * 16] = acc_o[mb][ni][r];
                if (l15 == 0) {
                    ml[(gb + q) * 2]     = m_run[mb][r];
                    ml[(gb + q) * 2 + 1] = l_run[mb][r];
                }
            }
        }
}

// ---------------- combine splits (+vmean for even layers) -> ob bf16 ----------------
__global__ __launch_bounds__(256) void comb_k(const float* __restrict__ Ou, const float* __restrict__ ml,
                                              const float* __restrict__ vm, u16* __restrict__ ob,
                                              int even, int nsplit, int NG, int Sq) {
    int g = blockIdx.y;
    int q = blockIdx.x * 4 + (threadIdx.x >> 6);
    int d = threadIdx.x & 63;
    if (q >= Sq) return;
    int h, sbase;
    if (even) { h = g >> 3; sbase = (g & 7) * Nn; } else { h = g; sbase = 0; }
    float M = -INFINITY;
    for (int s = 0; s < nsplit; ++s) M = fmaxf(M, ml[(((size_t)s * NG + g) * Sq + q) * 2]);
    float num = 0.f, den = 0.f;
    for (int s = 0; s < nsplit; ++s) {
        size_t base = ((size_t)s * NG + g) * Sq + q;
        float wgt = __expf(ml[base * 2] - M);
        den += wgt * ml[base * 2 + 1];
        num += wgt * Ou[base * 64 + d];
    }
    float o = num / den;
    if (even) o += vm[g * 64 + d];
    ob[(size_t)(sbase + q) * Dm + h * 64 + d] = f2bf(o);
}

extern "C" void kernel_launch(void* const* d_in, const int* in_sizes, int n_in,
                              void* d_out, int out_size, void* d_ws, size_t ws_size,
                              hipStream_t stream) {
    (void)in_sizes; (void)n_in; (void)out_size; (void)ws_size;
    const float* x       = (const float*)d_in[0];
    const float* W_patch = (const float*)d_in[1];
    const float* b_patch = (const float*)d_in[2];
    const float* cls     = (const float*)d_in[3];
    const float* pos     = (const float*)d_in[4];
    const float* ln1_g   = (const float*)d_in[5];
    const float* ln1_b   = (const float*)d_in[6];
    const float* qkv_w   = (const float*)d_in[7];
    const float* qkv_b   = (const float*)d_in[8];
    const float* proj_w  = (const float*)d_in[9];
    const float* proj_b  = (const float*)d_in[10];
    const float* ln2_g   = (const float*)d_in[11];
    const float* ln2_b   = (const float*)d_in[12];
    const float* fc1_w   = (const float*)d_in[13];
    const float* fc1_b   = (const float*)d_in[14];
    const float* fc2_w   = (const float*)d_in[15];
    const float* fc2_b   = (const float*)d_in[16];
    const float* lnf_g   = (const float*)d_in[17];
    const float* lnf_b   = (const float*)d_in[18];

    char* base = (char*)d_ws;
    auto alloc = [&](size_t bytes) { void* p = base; base += (bytes + 255) & ~(size_t)255; return p; };
    u16*   P    = (u16*)  alloc((size_t)MPAD * 768 * 2);
    u16*   Wq   = (u16*)  alloc((size_t)2304 * 768 * 2);
    u16*   Wp   = (u16*)  alloc((size_t)768 * 768 * 2);
    u16*   W1   = (u16*)  alloc((size_t)3072 * 768 * 2);
    u16*   W2   = (u16*)  alloc((size_t)768 * 3072 * 2);
    float* emb  = (float*)alloc((size_t)1568 * 768 * 4);
    float* h    = (float*)alloc((size_t)Sn * Dm * 4);
    u16*   a    = (u16*)  alloc((size_t)MPAD * 768 * 2);
    u16*   qkvb = (u16*)  alloc((size_t)Sn * 2304 * 2);
    u16*   ob   = (u16*)  alloc((size_t)MPAD * 768 * 2);
    u16*   mb   = (u16*)  alloc((size_t)MPAD * 3072 * 2);
    float* vm   = (float*)alloc((size_t)96 * 64 * 4);
    float* Ou   = (float*)alloc((size_t)3 * 12 * Sn * 64 * 4);
    float* ml   = (float*)alloc((size_t)3 * 12 * Sn * 2 * 4);
    float* Cp   = (float*)alloc((size_t)3 * MPAD * 2304 * 4);   // max over all gemms

    // ---- patch embed ----
    im2col_k<<<(1568 * 768 + 255) / 256, 256, 0, stream>>>(x, P);
    cvt_k<<<(768 * 768 + 255) / 256, 256, 0, stream>>>(W_patch, Wp, 768 * 768);
    mgemm_k<<<dim3(6, 13, 3), 256, 0, stream>>>(P, Wp, Cp, 768, 768, 256);
    ep_k<false, false, float><<<dim3(1, 1568), 256, 0, stream>>>(Cp, b_patch, nullptr, emb, 768, 3);
    build_h_k<<<(Sn * Dm + 255) / 256, 256, 0, stream>>>(emb, cls, pos, h);

    for (int i = 0; i < 12; ++i) {
        cvtT_layer_k<<<6912, 256, 0, stream>>>(
            qkv_w + (size_t)i * 768 * 2304, proj_w + (size_t)i * 768 * 768,
            fc1_w + (size_t)i * 768 * 3072, fc2_w + (size_t)i * 3072 * 768,
            Wq, Wp, W1, W2);
        ln_k<u16><<<Sn, 256, 0, stream>>>(h, ln1_g + i * Dm, ln1_b + i * Dm, a);
        mgemm_k<<<dim3(18, 13, 3), 256, 0, stream>>>(a, Wq, Cp, 2304, 768, 256);
        ep_k<false, false, u16><<<dim3(3, Sn), 256, 0, stream>>>(Cp, qkv_b + i * 2304, nullptr, qkvb, 2304, 3);
        if ((i & 1) == 0) {
            vmean_k<<<96, 64, 0, stream>>>(qkvb, vm);
            attn_mfma_k<<<dim3(2, 96, 1), 256, 0, stream>>>(qkvb, Ou, ml, 1, 1, 96, Nn);
            comb_k<<<dim3(50, 96), 256, 0, stream>>>(Ou, ml, vm, ob, 1, 1, 96, Nn);
        } else {
            attn_mfma_k<<<dim3(13, 12, 3), 256, 0, stream>>>(qkvb, Ou, ml, 0, 3, 12, Sn);
            comb_k<<<dim3(394, 12), 256, 0, stream>>>(Ou, ml, vm, ob, 0, 3, 12, Sn);
        }
        mgemm_k<<<dim3(6, 13, 4), 256, 0, stream>>>(ob, Wp, Cp, 768, 768, 192);
        ep_k<false, true, float><<<dim3(1, Sn), 256, 0, stream>>>(Cp, proj_b + i * Dm, h, h, 768, 4);
        ln_k<u16><<<Sn, 256, 0, stream>>>(h, ln2_g + i * Dm, ln2_b + i * Dm, a);
        mgemm_k<<<dim3(24, 13, 2), 256, 0, stream>>>(a, W1, Cp, 3072, 768, 384);
        ep_k<true, false, u16><<<dim3(3, Sn), 256, 0, stream>>>(Cp, fc1_b + i * MLPn, nullptr, mb, 3072, 2);
        mgemm_k<<<dim3(6, 13, 4), 256, 0, stream>>>(mb, W2, Cp, 768, 3072, 768);
        ep_k<false, true, float><<<dim3(1, Sn), 256, 0, stream>>>(Cp, fc2_b + i * Dm, h, h, 768, 4);
    }
    ln_k<float><<<Sn, 256, 0, stream>>>(h, lnf_g, lnf_b, (float*)d_out);
}